// Round 11
// baseline (252.558 us; speedup 1.0000x reference)
//
#include <hip/hip_runtime.h>
#include <hip/hip_bf16.h>

typedef __attribute__((ext_vector_type(4))) float f32x4;
typedef __attribute__((ext_vector_type(8))) short bf16x8;
typedef __attribute__((ext_vector_type(4))) short bf16x4v;

#define M_DIM 8192
#define N_DIM 4096
#define K_DIM 4096
#define NX (M_DIM * K_DIM)
#define NW (N_DIM * K_DIM)

#define BM 256
#define BN 256
#define BK 64
#define NKT (K_DIM / BK)   /* 64 */
#define THREADS 512

#define GLOAD_LDS16(g, l)                                                        \
  __builtin_amdgcn_global_load_lds(                                              \
      (const __attribute__((address_space(1))) void*)(g),                        \
      (__attribute__((address_space(3))) void*)(l), 16, 0, 0)

// ---------------------------------------------------------------------------
// Pass 1: fp32 -> bf16 conversion of x and W into workspace.
// ---------------------------------------------------------------------------
__global__ __launch_bounds__(256) void convert_bf16(const float* __restrict__ x,
                                                    const float* __restrict__ w,
                                                    short* __restrict__ ws) {
  const long stride = (long)gridDim.x * blockDim.x;
  const long total8 = ((long)NX + NW) / 8;
  for (long i = blockIdx.x * (long)blockDim.x + threadIdx.x; i < total8; i += stride) {
    const long base = i * 8;
    const float* src = (base < NX) ? (x + base) : (w + (base - NX));
    short* dst = ws + base;
    f32x4 a = *(const f32x4*)src;
    f32x4 b = *(const f32x4*)(src + 4);
    bf16x8 o;
    o[0] = (short)__bfloat16_as_ushort(__float2bfloat16(a[0]));
    o[1] = (short)__bfloat16_as_ushort(__float2bfloat16(a[1]));
    o[2] = (short)__bfloat16_as_ushort(__float2bfloat16(a[2]));
    o[3] = (short)__bfloat16_as_ushort(__float2bfloat16(a[3]));
    o[4] = (short)__bfloat16_as_ushort(__float2bfloat16(b[0]));
    o[5] = (short)__bfloat16_as_ushort(__float2bfloat16(b[1]));
    o[6] = (short)__bfloat16_as_ushort(__float2bfloat16(b[2]));
    o[7] = (short)__bfloat16_as_ushort(__float2bfloat16(b[3]));
    *(bf16x8*)dst = o;
  }
}

// ---------------------------------------------------------------------------
// Pass 2: 256x256 bf16 GEMM, BK=64, 8 waves (2M x 4N), double-buffered LDS.
// Rebalanced 4-phase schedule, 3 barriers/tile.  Per-wave read distribution
// 8/4/8/4 b128 per phase (was 12/4/8/0): b01 of tile t+1 is read at t.ph3
// from the next buffer (after the mid-ph3 publish), into tile-parity-
// alternating registers b01X/b01Y.
// Y = relu(X @ W^T + b)
//
// LDS per buffer (64 KiB): A rows 0-255 at [0,32KB), B at [32KB,64KB).
// Rows 128 B, 8 slots of 16 B, phys slot = logical ^ (row&7).
//
// Schedule per tile t (cur = buf[t&1], nxt = buf[(t+1)&1]):
//  ph0: read af<-cur.A[m0-3];              MFMA Q0(af, b01cur)
//  ph1: read b23<-cur.B[n2-3];             MFMA Q1(af, b23)
//       BARRIER  (seals cur.B reads: b01cur consumed t.ph0, b23 t.ph1)
//  ph2: stage B(t+2)->cur.B; read af<-cur.A[m4-7]; MFMA Q2(af, b01cur)
//       BARRIER  (seals cur.A reads: m0-3 consumed ph0/ph1, m4-7 ph2)
//  ph3: vmcnt(4)  (waits t+1's 8 loads; leaves B(t+2)'s 4 in flight)
//       BARRIER  (publishes t+1 residence)
//       stage A(t+2)->cur.A; read b01nxt<-nxt.B[n0-1]; MFMA Q3(af, b23)
//
// Race audit:
//  - stage B(t+2) at ph2 follows ph1's barrier; all waves' cur.B LDS reads
//    (b01cur at t-1.ph3, consumed t.ph0; b23 in-phase ph1) are complete.
//  - stage A(t+2) at ph3 follows ph2's barrier; cur.A reads in-phase.
//  - b01nxt / next-ph0 af reads of nxt follow the publish barrier.
//  - next tile's stage B(t+3) into nxt.B follows next ph1's barrier, by
//    which time every wave consumed b01nxt (next ph0's MFMA lgkm-waits it).
//  - Epilogue buf0 scratch: per-wave private; all buf0 reads complete
//    before tile 63's ph2 barrier.
// ---------------------------------------------------------------------------
__global__ __launch_bounds__(THREADS, 2) void gemm256_bf16(
    const short* __restrict__ Abf,   /* [M][K] bf16 */
    const short* __restrict__ Bbf,   /* [N][K] bf16 */
    const float* __restrict__ bias,
    float* __restrict__ Y) {
  __shared__ short lds[2 * 32768];   /* 128 KiB */
  char* const ldsb = (char*)lds;

  const int tid  = threadIdx.x;
  const int lane = tid & 63;
  const int wave = tid >> 6;       // 0..7
  const int wm   = wave >> 2;      // 0..1  (M half)
  const int wn   = wave & 3;       // 0..3  (N quarter)

  // XCD-aware bijective swizzle: 512 wgs = 8 XCDs x 64.
  const int lin = blockIdx.x + blockIdx.y * (N_DIM / BN);   // gridDim.x = 16
  const int swz = (lin & 7) * 64 + (lin >> 3);
  const int bx = swz & 15;         // N tile
  const int by = swz >> 4;         // M tile
  const long rowA0 = (long)by * BM;
  const long rowB0 = (long)bx * BN;

  // staging: one GLOAD issue = 512 thr x 16 B = 64 rows x 128 B.
  const int sg_col = (((lane & 7) ^ ((lane >> 3) & 7)) << 3);
  const int s_row  = wave * 8 + (lane >> 3);
  const int voff = s_row * K_DIM + sg_col;

  const short* uA = Abf + rowA0 * (long)K_DIM;
  const short* uB = Bbf + rowB0 * (long)K_DIM;

  // fragment-read per-lane byte offsets: row = frag*16 + (lane&15),
  // phys slot = kslot ^ (row&7) = kslot ^ (lane&7).
  const int offk0 = (lane & 15) * 128 + ((((lane >> 4)) ^ (lane & 7)) << 4);
  const int offk1 = (lane & 15) * 128 + (((4 + (lane >> 4)) ^ (lane & 7)) << 4);

// stage one half-tile (2 gloads). HALF: 0 = A rows 0-127, 1 = A rows 128-255,
// 2 = B rows 0-127, 3 = B rows 128-255.
#define STAGE_HALF(BOFF_, HALF_, TT) do {                                        \
    const short* u_ = ((HALF_) < 2 ? uA : uB) +                                  \
                      (long)(((HALF_) & 1) * 128) * K_DIM + (long)(TT) * BK;     \
    char* l_ = ldsb + (BOFF_) + ((HALF_) < 2 ? 0 : 32768) +                      \
               ((HALF_) & 1) * 16384 + wave * 1024;                              \
    GLOAD_LDS16(u_ + voff, l_);                                                  \
    GLOAD_LDS16(u_ + 64 * K_DIM + voff, l_ + 8192);                              \
  } while (0)

#define PH_READ_A(DST, BOFF_, MADD) do {                                         \
    const char* pa_ = ldsb + (BOFF_) + wm * 16384 + (MADD);                      \
    _Pragma("unroll")                                                            \
    for (int m_ = 0; m_ < 4; ++m_) {                                             \
      DST[m_][0] = *(const bf16x8*)(pa_ + m_ * 2048 + offk0);                    \
      DST[m_][1] = *(const bf16x8*)(pa_ + m_ * 2048 + offk1);                    \
    }                                                                            \
  } while (0)

#define PH_READ_B(DST, BOFF_, NADD) do {                                         \
    const char* pb_ = ldsb + (BOFF_) + 32768 + wn * 8192 + (NADD);               \
    _Pragma("unroll")                                                            \
    for (int n_ = 0; n_ < 2; ++n_) {                                             \
      DST[n_][0] = *(const bf16x8*)(pb_ + n_ * 2048 + offk0);                    \
      DST[n_][1] = *(const bf16x8*)(pb_ + n_ * 2048 + offk1);                    \
    }                                                                            \
  } while (0)

#define MFMA16(AF, BF, MB, NB) do {                                              \
    __builtin_amdgcn_s_setprio(1);                                               \
    _Pragma("unroll")                                                            \
    for (int kk_ = 0; kk_ < 2; ++kk_)                                            \
      _Pragma("unroll")                                                          \
      for (int m_ = 0; m_ < 4; ++m_)                                             \
        _Pragma("unroll")                                                        \
        for (int n_ = 0; n_ < 2; ++n_)                                           \
          acc[(MB) + m_][(NB) + n_] = __builtin_amdgcn_mfma_f32_16x16x32_bf16(   \
              AF[m_][kk_], BF[n_][kk_], acc[(MB) + m_][(NB) + n_], 0, 0, 0);     \
    __builtin_amdgcn_s_setprio(0);                                               \
  } while (0)

// One K-tile.  BCUR = b01 regs of tile T (already loaded); BNXT = b01 regs
// of tile T+1 (read at ph3).  VM: 4 = steady vmcnt(4), 0 = drain, -1 = last.
// RDNXT: read b01nxt at ph3.
#define TILE(BOFF_, NOFF_, T, DO_ST, BCUR, BNXT, RDNXT, VM) do {                 \
    /* ph0 */                                                                    \
    PH_READ_A(af, BOFF_, 0);                                                     \
    MFMA16(af, BCUR, 0, 0);                                                      \
    /* ph1 */                                                                    \
    PH_READ_B(b23, BOFF_, 4096);                                                 \
    MFMA16(af, b23, 0, 2);                                                       \
    __builtin_amdgcn_s_barrier();                                                \
    /* ph2 */                                                                    \
    if (DO_ST) { STAGE_HALF(BOFF_, 2, (T) + 2); STAGE_HALF(BOFF_, 3, (T) + 2); } \
    PH_READ_A(af, BOFF_, 8192);                                                  \
    MFMA16(af, BCUR, 4, 0);                                                      \
    __builtin_amdgcn_s_barrier();                                                \
    /* ph3 */                                                                    \
    if ((VM) == 4)      asm volatile("s_waitcnt vmcnt(4)" ::: "memory");         \
    else if ((VM) == 0) asm volatile("s_waitcnt vmcnt(0)" ::: "memory");         \
    if ((VM) >= 0) __builtin_amdgcn_s_barrier();   /* publish t+1 */             \
    if (DO_ST) { STAGE_HALF(BOFF_, 0, (T) + 2); STAGE_HALF(BOFF_, 1, (T) + 2); } \
    if (RDNXT) PH_READ_B(BNXT, NOFF_, 0);                                        \
    MFMA16(af, b23, 4, 2);                                                       \
  } while (0)

  f32x4 acc[8][4];
#pragma unroll
  for (int i = 0; i < 8; ++i)
#pragma unroll
    for (int j = 0; j < 4; ++j) acc[i][j] = (f32x4)0.0f;

  bf16x8 af[4][2], b01X[2][2], b01Y[2][2], b23[2][2];

  // ---- prologue: stage tiles 0 and 1 fully; read b01(tile0) ----
  STAGE_HALF(0, 0, 0);
  STAGE_HALF(0, 1, 0);
  STAGE_HALF(0, 2, 0);
  STAGE_HALF(0, 3, 0);
  STAGE_HALF(65536, 2, 1);
  STAGE_HALF(65536, 3, 1);
  STAGE_HALF(65536, 0, 1);
  STAGE_HALF(65536, 1, 1);
  asm volatile("s_waitcnt vmcnt(8)" ::: "memory");   // tile 0 resident
  __builtin_amdgcn_s_barrier();
  PH_READ_B(b01X, 0, 0);

  // ---- main loop: 2 tiles per iteration, tiles 0..61 ----
  for (int tp = 0; tp < NKT / 2 - 1; ++tp) {
    const int t0 = 2 * tp;
    TILE(0,     65536, t0,     1, b01X, b01Y, 1, 4);
    TILE(65536, 0,     t0 + 1, 1, b01Y, b01X, 1, 4);
  }
  // ---- tail: tile 62 (no stage; drain + publish 63; read b01(63)), 63 ----
  TILE(0,     65536, NKT - 2, 0, b01X, b01Y, 1, 0);
  TILE(65536, 0,     NKT - 1, 0, b01Y, b01X, 0, -1);

#undef TILE
#undef MFMA16
#undef PH_READ_B
#undef PH_READ_A
#undef STAGE_HALF

  // ---- epilogue: per-wave LDS transpose -> 128-B-segment f32x4 stores ----
  {
    char* scr = ldsb + wave * 8192;
    const int c0 = lane & 15;
    const int r0 = (lane >> 4) * 4;
    const int rd_row = lane >> 3;        // 0..7
    const int rd_ch  = (lane & 7) * 16;  // 16-B chunk within 128-B row
#pragma unroll
    for (int jp = 0; jp < 2; ++jp) {
      const long gcb = rowB0 + wn * 64 + jp * 32 + (lane & 7) * 4;
      const f32x4 bv4 = *(const f32x4*)&bias[gcb];
#pragma unroll
      for (int i = 0; i < 8; ++i) {
#pragma unroll
        for (int r = 0; r < 4; ++r) {
          *(float*)(scr + (r0 + r) * 144 + c0 * 4)      = acc[i][2 * jp + 0][r];
          *(float*)(scr + (r0 + r) * 144 + 64 + c0 * 4) = acc[i][2 * jp + 1][r];
        }
        f32x4 v0 = *(const f32x4*)(scr + rd_row * 144 + rd_ch);
        f32x4 v1 = *(const f32x4*)(scr + (8 + rd_row) * 144 + rd_ch);
        v0 += bv4;
        v1 += bv4;
#pragma unroll
        for (int e = 0; e < 4; ++e) {
          v0[e] = fmaxf(v0[e], 0.0f);
          v1[e] = fmaxf(v1[e], 0.0f);
        }
        const long gr = rowA0 + wm * 128 + i * 16;
        *(f32x4*)&Y[(gr + rd_row) * (long)N_DIM + gcb]     = v0;
        *(f32x4*)&Y[(gr + 8 + rd_row) * (long)N_DIM + gcb] = v1;
      }
    }
  }
}

// ---------------------------------------------------------------------------
// Fallback (only if ws too small): fp32 reg-staged 128^2 kernel.
// ---------------------------------------------------------------------------
#define FBM 128
#define FBK 32
#define FLDSS 40
__global__ __launch_bounds__(256) void fallback_gemm(
    const float* __restrict__ X, const float* __restrict__ W,
    const float* __restrict__ bias, float* __restrict__ Y) {
  __shared__ short As[FBM * FLDSS];
  __shared__ short Bs[FBM * FLDSS];
  const int tid = threadIdx.x, lane = tid & 63, wave = tid >> 6;
  const int wm = (wave >> 1) * 64, wn = (wave & 1) * 64;
  const long rowA0 = (long)blockIdx.y * FBM, rowB0 = (long)blockIdx.x * FBM;
  const int srow = tid >> 3, scol = (tid & 7) * 4;
  const float* Aptr = X + (rowA0 + srow) * (long)K_DIM + scol;
  const float* Bptr = W + (rowB0 + srow) * (long)K_DIM + scol;
  f32x4 ra[4], rb[4];
#pragma unroll
  for (int i = 0; i < 4; ++i) {
    ra[i] = *(const f32x4*)(Aptr + (long)i * 32 * K_DIM);
    rb[i] = *(const f32x4*)(Bptr + (long)i * 32 * K_DIM);
  }
  f32x4 acc[4][4];
#pragma unroll
  for (int i = 0; i < 4; ++i)
#pragma unroll
    for (int j = 0; j < 4; ++j) acc[i][j] = (f32x4)0.0f;
  for (int kt = 0; kt < K_DIM / FBK; ++kt) {
    __syncthreads();
#pragma unroll
    for (int i = 0; i < 4; ++i) {
      bf16x4v pa, pb;
#pragma unroll
      for (int j = 0; j < 4; ++j) {
        pa[j] = (short)__bfloat16_as_ushort(__float2bfloat16(ra[i][j]));
        pb[j] = (short)__bfloat16_as_ushort(__float2bfloat16(rb[i][j]));
      }
      *(bf16x4v*)&As[(i * 32 + srow) * FLDSS + scol] = pa;
      *(bf16x4v*)&Bs[(i * 32 + srow) * FLDSS + scol] = pb;
    }
    if (kt + 1 < K_DIM / FBK) {
      const float* An = Aptr + (kt + 1) * FBK;
      const float* Bn = Bptr + (kt + 1) * FBK;
#pragma unroll
      for (int i = 0; i < 4; ++i) {
        ra[i] = *(const f32x4*)(An + (long)i * 32 * K_DIM);
        rb[i] = *(const f32x4*)(Bn + (long)i * 32 * K_DIM);
      }
    }
    __syncthreads();
    bf16x8 af[4], bfr[4];
#pragma unroll
    for (int i = 0; i < 4; ++i) {
      af[i]  = *(const bf16x8*)&As[(wm + i * 16 + (lane & 15)) * FLDSS + (lane >> 4) * 8];
      bfr[i] = *(const bf16x8*)&Bs[(wn + i * 16 + (lane & 15)) * FLDSS + (lane >> 4) * 8];
    }
#pragma unroll
    for (int i = 0; i < 4; ++i)
#pragma unroll
      for (int j = 0; j < 4; ++j)
        acc[i][j] = __builtin_amdgcn_mfma_f32_16x16x32_bf16(af[i], bfr[j], acc[i][j], 0, 0, 0);
  }
  const int r0 = (lane >> 4) * 4, c0 = lane & 15;
#pragma unroll
  for (int j = 0; j < 4; ++j) {
    const long gc = rowB0 + wn + j * 16 + c0;
    const float bv = bias[gc];
#pragma unroll
    for (int i = 0; i < 4; ++i) {
      const long gr0 = rowA0 + wm + i * 16 + r0;
#pragma unroll
      for (int r = 0; r < 4; ++r) {
        float v = acc[i][j][r] + bv;
        Y[(gr0 + r) * (long)N_DIM + gc] = fmaxf(v, 0.0f);
      }
    }
  }
}

extern "C" void kernel_launch(void* const* d_in, const int* in_sizes, int n_in,
                              void* d_out, int out_size, void* d_ws, size_t ws_size,
                              hipStream_t stream) {
  const float* x = (const float*)d_in[0];
  const float* w = (const float*)d_in[1];
  const float* b = (const float*)d_in[2];
  float* y = (float*)d_out;

  const size_t need = (size_t)(NX + NW) * sizeof(short);
  if (ws_size >= need) {
    short* ws = (short*)d_ws;
    convert_bf16<<<2048, 256, 0, stream>>>(x, w, ws);
    dim3 grid(N_DIM / BN, M_DIM / BM);
    gemm256_bf16<<<grid, dim3(THREADS), 0, stream>>>(ws, ws + NX, b, y);
  } else {
    dim3 grid(N_DIM / FBM, M_DIM / FBM);
    fallback_gemm<<<grid, dim3(256), 0, stream>>>(x, w, b, y);
  }
}